// Round 2
// baseline (725.480 us; speedup 1.0000x reference)
//
#include <hip/hip_runtime.h>

#define FEAT 41024
#define HID  256
#define BATCH 2048
#define MTOT 4096
#define BK 32
#define NBK (FEAT / BK)            /* 1282 */
#define KSPLIT 16
#define MT 256
#define ACCN ((size_t)MTOT * HID)  /* 1048576 floats per split slice */

typedef float    f32x4  __attribute__((ext_vector_type(4)));
typedef float    f32x16 __attribute__((ext_vector_type(16)));
typedef _Float16 f16x8  __attribute__((ext_vector_type(8)));

#define GLDS(g, s) __builtin_amdgcn_global_load_lds(                      \
    (const __attribute__((address_space(1))) void*)(g),                   \
    (__attribute__((address_space(3))) void*)(s), 16, 0, 0)

// ---------------- zero kernel (atomic-fallback path only) ----------------
__global__ __launch_bounds__(512) void zero_ws_k(float* __restrict__ p) {
    int i = blockIdx.x * 512 + threadIdx.x;
    ((f32x4*)p)[i] = (f32x4)(0.0f);
}

// ---------------- input-layer GEMM: [4096,41024] x [41024,256]^T ----------------
// 1024 threads = 16 waves (4x4), wave tile 64x64 of v_mfma_f32_32x32x16_f16.
// fp32 staged direct-to-LDS via global_load_lds (double-buffered, 1 barrier/iter),
// f32->f16 conversion fused into the LDS->fragment load. 16 waves/CU resident.
__global__ __launch_bounds__(1024, 4) void gemm_in_k(
    const float* __restrict__ wfeat, const float* __restrict__ bfeat,
    const float* __restrict__ Win, float* __restrict__ part, int use_atomic)
{
    // [buf][ A: 256 rows x 32 floats | B: 256 rows x 32 floats ] = 2 x 64 KB
    __shared__ __align__(16) float lds[2][16384];

    const int tid = threadIdx.x;
    const int w   = tid >> 6;
    const int l   = tid & 63;
    const int l31 = l & 31;
    const int lh  = l >> 5;
    const int wm  = w >> 2;   // 0..3 (row group)
    const int wn  = w & 3;    // 0..3 (col group)

    // XCD-aware remap: co-locate each split's blocks (2 splits per XCD L2)
    const int flat  = blockIdx.x + (blockIdx.y << 4);
    const int xcd   = flat & 7;
    const int jj    = flat >> 3;
    const int split = (xcd << 1) | (jj & 1);
    const int mtile = jj >> 1;

    const int it_beg = (split * NBK) / KSPLIT;
    const int it_end = ((split + 1) * NBK) / KSPLIT;
    const int m0 = mtile * MT;
    const float* Ab = (m0 < BATCH) ? (wfeat + (size_t)m0 * FEAT)
                                   : (bfeat + (size_t)(m0 - BATCH) * FEAT);

    // Staging: LDS chunk q (16B) holds row q>>3, in-row chunk c=q&7.
    // Swizzle at 32B-pair granularity: LDS pair p of row r holds global pair p^(r&3).
    // Thread covers chunks q0 = w*64+l (rows 0..127) and q0+1024 (rows 128..255),
    // for both A and B.
    const int row0 = (w << 3) + (l >> 3);            // 0..127
    const int c    = l & 7;
    const int gseg = ((((c >> 1) ^ (row0 & 3)) << 1) | (c & 1));
    const size_t ga0 = (size_t)row0 * FEAT + gseg * 4;
    const size_t ga1 = (size_t)(row0 + 128) * FEAT + gseg * 4;  // (row0+128)&3 == row0&3
    const int lb = w << 8;                            // wave LDS base, floats

    f32x16 acc[2][2];
    #pragma unroll
    for (int a = 0; a < 2; ++a)
        #pragma unroll
        for (int b = 0; b < 2; ++b)
            acc[a][b] = (f32x16)(0.0f);

    // precompute fragment row constants
    int rA[2], rB[2];
    #pragma unroll
    for (int mf = 0; mf < 2; ++mf) rA[mf] = wm * 64 + mf * 32 + l31;
    #pragma unroll
    for (int nf = 0; nf < 2; ++nf) rB[nf] = wn * 64 + nf * 32 + l31;

    #define STAGE(bufi, k0f)                                                   \
        do {                                                                   \
            float* base = &lds[bufi][0];                                       \
            GLDS(Ab  + ga0 + (k0f), base + lb);                                \
            GLDS(Ab  + ga1 + (k0f), base + 4096  + lb);                        \
            GLDS(Win + ga0 + (k0f), base + 8192  + lb);                        \
            GLDS(Win + ga1 + (k0f), base + 12288 + lb);                        \
        } while (0)

    STAGE(0, (size_t)it_beg * BK);
    int buf = 0;

    for (int it = it_beg; it < it_end; ++it) {
        __syncthreads();  // drains this slab's loads (vmcnt) + syncs buffers
        if (it + 1 < it_end) {
            const size_t k0n = (size_t)(it + 1) * BK;
            if (buf == 0) STAGE(1, k0n); else STAGE(0, k0n);
        }
        const float* A_ = &lds[buf][0];
        const float* B_ = &lds[buf][8192];

        #pragma unroll
        for (int ks = 0; ks < 2; ++ks) {
            f16x8 af[2], bf[2];
            #pragma unroll
            for (int mf = 0; mf < 2; ++mf) {
                const int r = rA[mf];
                const int p = (ks * 2 + lh) ^ (r & 3);
                const float* src = &A_[r * 32 + p * 8];
                const f32x4 x0 = *(const f32x4*)(src);
                const f32x4 x1 = *(const f32x4*)(src + 4);
                f16x8 t;
                #pragma unroll
                for (int e = 0; e < 4; ++e) {
                    t[e]     = (_Float16)x0[e];
                    t[4 + e] = (_Float16)x1[e];
                }
                af[mf] = t;
            }
            #pragma unroll
            for (int nf = 0; nf < 2; ++nf) {
                const int r = rB[nf];
                const int p = (ks * 2 + lh) ^ (r & 3);
                const float* src = &B_[r * 32 + p * 8];
                const f32x4 x0 = *(const f32x4*)(src);
                const f32x4 x1 = *(const f32x4*)(src + 4);
                f16x8 t;
                #pragma unroll
                for (int e = 0; e < 4; ++e) {
                    t[e]     = (_Float16)x0[e];
                    t[4 + e] = (_Float16)x1[e];
                }
                bf[nf] = t;
            }
            #pragma unroll
            for (int mf = 0; mf < 2; ++mf)
                #pragma unroll
                for (int nf = 0; nf < 2; ++nf)
                    acc[mf][nf] = __builtin_amdgcn_mfma_f32_32x32x16_f16(
                        af[mf], bf[nf], acc[mf][nf], 0, 0, 0);
        }
        buf ^= 1;
    }

    // epilogue: C/D layout col=lane&31, row=(reg&3)+8*(reg>>2)+4*(lane>>5)
    float* dst = part + (use_atomic ? (size_t)0 : (size_t)split * ACCN);
    #pragma unroll
    for (int mf = 0; mf < 2; ++mf)
        #pragma unroll
        for (int nf = 0; nf < 2; ++nf) {
            const int gcol = wn * 64 + nf * 32 + l31;
            #pragma unroll
            for (int r = 0; r < 16; ++r) {
                const int rrow = (r & 3) + 8 * (r >> 2) + 4 * lh;
                const int grow = m0 + wm * 64 + mf * 32 + rrow;
                const size_t idx = (size_t)grow * HID + gcol;
                if (use_atomic) atomicAdd(&dst[idx], acc[mf][nf][r]);
                else            dst[idx] = acc[mf][nf][r];
            }
        }
}

// ---------------- split-K reduce + bias/relu + tiny MLP ----------------
__global__ __launch_bounds__(256) void mlp_k(
    const float* __restrict__ part, int nparts,
    const float* __restrict__ b_in,
    const float* __restrict__ W_h1, const float* __restrict__ b_h1,
    const float* __restrict__ W_h2, const float* __restrict__ b_h2,
    const float* __restrict__ W_out, const float* __restrict__ b_out,
    float* __restrict__ out)
{
    __shared__ _Float16 W1h[512 * 32];  // transposed [j][i], XOR-swizzled, 32 KB
    __shared__ float    W2T[32 * 33];   // transposed [ii][i'], padded
    __shared__ float    Wo[32];
    __shared__ float    cbuf[4 * 512];  // per-wave combined vector

    const int tid = threadIdx.x;
    #pragma unroll
    for (int u = 0; u < 64; ++u) {
        const int f = tid + 256 * u;
        const int i = f >> 9, j = f & 511;
        W1h[j * 32 + (i ^ (j & 31))] = (_Float16)W_h1[i * 512 + j];
    }
    #pragma unroll
    for (int u = 0; u < 4; ++u) {
        const int f = tid + 256 * u;
        const int a = f >> 5, b = f & 31;
        W2T[b * 33 + a] = W_h2[a * 32 + b];
    }
    if (tid < 32) Wo[tid] = W_out[tid];
    __syncthreads();

    const int wid = tid >> 6, lane = tid & 63, l31 = lane & 31, lh = lane >> 5;
    const float bh1 = b_h1[l31], bh2 = b_h2[l31], bo = b_out[0];
    float* cw = &cbuf[wid * 512];

    for (int r = 0; r < 2; ++r) {
        const int row = blockIdx.x * 8 + wid * 2 + r;
        const int jb  = lane * 8;  // lanes 0-31 white half, 32-63 black half
        const size_t srow = (size_t)(lh ? (row + BATCH) : row) * HID + (jb & 255);
        f32x4 v0 = (f32x4)(0.0f), v1 = (f32x4)(0.0f);
        for (int s = 0; s < nparts; ++s) {
            const float* p = part + (size_t)s * ACCN + srow;
            v0 += *(const f32x4*)p;
            v1 += *(const f32x4*)(p + 4);
        }
        const f32x4 bi0 = *(const f32x4*)(b_in + (jb & 255));
        const f32x4 bi1 = *(const f32x4*)(b_in + (jb & 255) + 4);
        f32x4 c0, c1;
        #pragma unroll
        for (int e = 0; e < 4; ++e) {
            c0[e] = fmaxf(v0[e] + bi0[e], 0.0f);
            c1[e] = fmaxf(v1[e] + bi1[e], 0.0f);
        }
        *(f32x4*)&cw[jb]     = c0;
        *(f32x4*)&cw[jb + 4] = c1;
        __syncthreads();

        float p1 = 0.0f;
        #pragma unroll 8
        for (int jj = 0; jj < 256; ++jj) {
            const int j = lh * 256 + jj;
            p1 = fmaf((float)W1h[j * 32 + (l31 ^ (jj & 31))], cw[j], p1);
        }
        p1 += __shfl_xor(p1, 32);
        const float x1 = fmaxf(p1 + bh1, 0.0f);

        float p2 = 0.0f;
        #pragma unroll
        for (int ii = 0; ii < 32; ++ii) {
            const float xv = __shfl(x1, ii);
            p2 = fmaf(W2T[ii * 33 + l31], xv, p2);
        }
        const float x2 = fmaxf(p2 + bh2, 0.0f);

        float ov = x2 * Wo[l31];
        ov += __shfl_xor(ov, 16);
        ov += __shfl_xor(ov, 8);
        ov += __shfl_xor(ov, 4);
        ov += __shfl_xor(ov, 2);
        ov += __shfl_xor(ov, 1);
        if (lane == 0) out[row] = ov + bo;
        __syncthreads();
    }
}

extern "C" void kernel_launch(void* const* d_in, const int* in_sizes, int n_in,
                              void* d_out, int out_size, void* d_ws, size_t ws_size,
                              hipStream_t stream) {
    const float* wf   = (const float*)d_in[0];
    const float* blf  = (const float*)d_in[1];
    const float* Win  = (const float*)d_in[2];
    const float* bin  = (const float*)d_in[3];
    const float* Wh1  = (const float*)d_in[4];
    const float* bh1  = (const float*)d_in[5];
    const float* Wh2  = (const float*)d_in[6];
    const float* bh2  = (const float*)d_in[7];
    const float* Wout = (const float*)d_in[8];
    const float* bout = (const float*)d_in[9];
    float* out = (float*)d_out;
    float* ws  = (float*)d_ws;

    const size_t need = (size_t)KSPLIT * ACCN * sizeof(float);  // 64 MB
    const int use_atomic = (ws_size < need) ? 1 : 0;

    if (use_atomic) zero_ws_k<<<2048, 512, 0, stream>>>(ws);  // zero full 16 MB slice
    dim3 g(MTOT / MT, KSPLIT);
    gemm_in_k<<<g, 1024, 0, stream>>>(wf, blf, Win, ws, use_atomic);
    mlp_k<<<BATCH / 8, 256, 0, stream>>>(ws, use_atomic ? 1 : KSPLIT,
                                         bin, Wh1, bh1, Wh2, bh2, Wout, bout, out);
}